// Round 11
// baseline (32.130 us; speedup 1.0000x reference)
//
#include <hip/hip_runtime.h>

#define BATCH 8
#define NTOK 4096
#define CH 256
#define IMG 1024
#define PATCH 16
#define CHUNKS 32                    // blocks per (batch, input)
#define TPB (NTOK / CHUNKS)          // 128 tokens per block
#define PART_STRIDE 520              // per-block partial slab (floats)
#define NBLK_STATS (2 * BATCH * CHUNKS)  // 512
#define SB (NBLK_STATS * PART_STRIDE)    // slot region base (floats)
#define CNTF (SB + 512)                  // counter region base (floats)

#define SCOPE __HIP_MEMORY_SCOPE_AGENT

// R6 lesson: per-block __threadfence = per-block L2 writeback = disaster.
// R11 protocol: cross-block data via agent-scope RELAXED atomic ops (sc1,
// per-line coherent-point access, NO cache flush); ordering via
// s_waitcnt vmcnt(0) before a relaxed arrival-counter bump.
// ws: 512 slabs of 520 floats; slots 64x8 floats at SB; counters at CNTF:
//   cnt1[8] (arrivals per batch), cnt2 (slice-finalizer count) - memset'd 0.

__device__ __forceinline__ float aload(const float* p) {
    return __hip_atomic_load(p, __ATOMIC_RELAXED, SCOPE);
}
__device__ __forceinline__ void astore(float* p, float v) {
    __hip_atomic_store(p, v, __ATOMIC_RELAXED, SCOPE);
}

__global__ __launch_bounds__(256) void fused_kernel(
    const float* __restrict__ ep_e, const float* __restrict__ ep_m,
    const float* __restrict__ q_e,  const float* __restrict__ q_m,
    float* __restrict__ ws, float* __restrict__ out)
{
    const int bid = blockIdx.x;
    const int tid = threadIdx.x;

    const bool is_q = (bid >= BATCH * CHUNKS);
    const int lb    = bid & (BATCH * CHUNKS - 1);
    const int b     = lb >> 5;                  // /CHUNKS
    const int start = (lb & (CHUNKS - 1)) * TPB;

    const float* __restrict__ embed = is_q ? q_e : ep_e;
    const float* __restrict__ mask  = is_q ? q_m : ep_m;

    const int w = tid >> 6, lane = tid & 63, cbase = lane << 2;

    float4 accW = {0.f, 0.f, 0.f, 0.f};
    float4 accS = {0.f, 0.f, 0.f, 0.f};
    float accA = 0.f, accB = 0.f, accm = 0.f;

    const float* ebase = embed + (size_t)(b * NTOK + start) * CH + cbase;
    const size_t mbase = (size_t)b * IMG * IMG;

    const int t0 = w * 32;   // this wave's 32 contiguous tokens
    #pragma unroll
    for (int bat = 0; bat < 4; ++bat) {
        float4 e[8];
        float  mm[8];
        #pragma unroll
        for (int k = 0; k < 8; ++k) {
            const int t = t0 + bat * 8 + k;
            const int n = start + t;
            mm[k] = mask[mbase + (size_t)((n >> 6) * PATCH) * IMG + (size_t)((n & 63) * PATCH)];
            e[k]  = *reinterpret_cast<const float4*>(ebase + (size_t)t * CH);
        }
        #pragma unroll
        for (int k = 0; k < 8; ++k) {
            const float m = mm[k];
            accW.x += m * e[k].x; accW.y += m * e[k].y;
            accW.z += m * e[k].z; accW.w += m * e[k].w;
            accS.x += e[k].x;     accS.y += e[k].y;
            accS.z += e[k].z;     accS.w += e[k].w;
            if (is_q) {
                const float d = e[k].x * e[k].x + e[k].y * e[k].y
                              + e[k].z * e[k].z + e[k].w * e[k].w;
                accA += m * d;
                accB += d;
            }
            accm += m;   // wave-uniform
        }
    }

    // ---- cross-wave reduce (all 4 waves cover the same 256 channels) ----
    __shared__ __align__(16) float ldsW[4][CH];
    __shared__ __align__(16) float ldsS[4][CH];
    __shared__ float ldsA[4], ldsB[4], ldsM[4];

    *reinterpret_cast<float4*>(&ldsW[w][cbase]) = accW;
    *reinterpret_cast<float4*>(&ldsS[w][cbase]) = accS;
    if (is_q) {
        for (int off = 32; off > 0; off >>= 1) {
            accA += __shfl_down(accA, off, 64);
            accB += __shfl_down(accB, off, 64);
        }
    }
    if (lane == 0) { ldsA[w] = accA; ldsB[w] = accB; ldsM[w] = accm; }
    __syncthreads();

    // ---- publish partials via coherent (sc1) stores ----
    float* p = ws + (size_t)bid * PART_STRIDE;
    const int c = tid;
    astore(&p[c],      ldsW[0][c] + ldsW[1][c] + ldsW[2][c] + ldsW[3][c]);
    astore(&p[CH + c], ldsS[0][c] + ldsS[1][c] + ldsS[2][c] + ldsS[3][c]);
    if (tid == 0) {
        astore(&p[512], ldsM[0] + ldsM[1] + ldsM[2] + ldsM[3]);
        astore(&p[513], is_q ? (ldsA[0] + ldsA[1] + ldsA[2] + ldsA[3]) : 0.f);
        astore(&p[514], is_q ? (ldsB[0] + ldsB[1] + ldsB[2] + ldsB[3]) : 0.f);
    }
    asm volatile("s_waitcnt vmcnt(0)" ::: "memory");   // stores at coherent pt
    __syncthreads();                                   // all waves done

    // ---- arrival: last 8 arrivers of this batch become slice-finalizers ----
    unsigned int* cnt1 = (unsigned int*)(ws + CNTF);
    unsigned int* cnt2 = (unsigned int*)(ws + CNTF + 8);
    __shared__ int s_role;
    if (tid == 0) {
        unsigned old = __hip_atomic_fetch_add(&cnt1[b], 1u, __ATOMIC_RELAXED, SCOPE);
        s_role = (old >= 2 * CHUNKS - 8) ? (int)(old - (2 * CHUNKS - 8)) : -1;
    }
    __syncthreads();
    const int g = s_role;          // slice 0..7 or -1
    if (g < 0) return;

    if (tid == 0) {                // roles 0..6 wait for stragglers
        while (__hip_atomic_load(&cnt1[b], __ATOMIC_RELAXED, SCOPE) < 2u * CHUNKS)
            __builtin_amdgcn_s_sleep(2);
    }
    __syncthreads();

    // ============ slice finalize: channels [g*32, g*32+32) ============
    float* fls = &ldsW[0][0];      // reuse stats LDS as [4][8][32]
    const int r  = tid >> 5;       // chunk row 0..7
    const int cc = tid & 31;       // channel within slice
    const int ch = g * 32 + cc;

    float pn = 0.f, se = 0.f, uu = 0.f, vv = 0.f;
    #pragma unroll
    for (int pp = 0; pp < 4; ++pp) {
        const int k = r + 8 * pp;
        const float* pe = ws + (size_t)(b * CHUNKS + k) * PART_STRIDE;
        const float* pq = pe + (size_t)(BATCH * CHUNKS) * PART_STRIDE;
        pn += aload(&pe[ch]); se += aload(&pe[CH + ch]);
        uu += aload(&pq[ch]); vv += aload(&pq[CH + ch]);
    }

    // batch scalars (redundant per slice block, 64 coherent loads)
    if (tid < 32) {
        const float* pe = ws + (size_t)(b * CHUNKS + tid) * PART_STRIDE;
        float v = aload(&pe[512]);
        #pragma unroll
        for (int off = 16; off; off >>= 1) v += __shfl_xor(v, off, 32);
        if (tid == 0) ldsA[0] = v;                       // cnt
    } else if (tid < 64) {
        const float* pq = ws + (size_t)(BATCH * CHUNKS + b * CHUNKS + (tid - 32)) * PART_STRIDE;
        float n0 = aload(&pq[512]), a0 = aload(&pq[513]), b0 = aload(&pq[514]);
        #pragma unroll
        for (int off = 16; off; off >>= 1) {
            n0 += __shfl_xor(n0, off, 32);
            a0 += __shfl_xor(a0, off, 32);
            b0 += __shfl_xor(b0, off, 32);
        }
        if (tid == 32) { ldsA[1] = n0; ldsA[2] = a0; ldsA[3] = b0; }  // np,A,Bv
    }

    fls[0 * 256 + r * 32 + cc] = pn;
    fls[1 * 256 + r * 32 + cc] = se;
    fls[2 * 256 + r * 32 + cc] = uu;
    fls[3 * 256 + r * 32 + cc] = vv;
    __syncthreads();

    __shared__ int s_tail;
    if (tid < 32) {
        float PN = 0.f, SE = 0.f, UU = 0.f, VV = 0.f;
        #pragma unroll
        for (int rr = 0; rr < 8; ++rr) {
            PN += fls[0 * 256 + rr * 32 + tid];
            SE += fls[1 * 256 + rr * 32 + tid];
            UU += fls[2 * 256 + rr * 32 + tid];
            VV += fls[3 * 256 + rr * 32 + tid];
        }
        const float cnt  = ldsA[0];
        const float id_p = 1.f / (cnt + 0.1f);
        const float id_n = 1.f / (((float)NTOK - cnt) + 0.1f);
        const float pc = PN * id_p;
        const float nc = (SE - PN) * id_n;
        float tx = UU * pc;
        float ty = (VV - UU) * nc;
        float tz = pc * pc;
        float tw = nc * nc;
        #pragma unroll
        for (int off = 16; off; off >>= 1) {
            tx += __shfl_xor(tx, off, 32);
            ty += __shfl_xor(ty, off, 32);
            tz += __shfl_xor(tz, off, 32);
            tw += __shfl_xor(tw, off, 32);
        }
        if (tid == 0) {
            float* o = ws + SB + (size_t)(b * 8 + g) * 8;
            astore(&o[0], tx); astore(&o[1], ty);
            astore(&o[2], tz); astore(&o[3], tw);
            astore(&o[4], ldsA[0]); astore(&o[5], ldsA[1]);
            astore(&o[6], ldsA[2]); astore(&o[7], ldsA[3]);
            asm volatile("s_waitcnt vmcnt(0)" ::: "memory");
            unsigned old2 = __hip_atomic_fetch_add(cnt2, 1u, __ATOMIC_RELAXED, SCOPE);
            s_tail = (old2 == 8u * BATCH - 1u);
        }
    }
    __syncthreads();
    if (!s_tail) return;

    // ============ tail: 64 lanes, slot l = b*8+g ============
    if (tid < 64) {
        const int l = tid;
        const float* o  = ws + SB + (size_t)l * 8;
        const float* o0 = ws + SB + (size_t)(l & ~7) * 8;
        float tx = aload(&o[0]), ty = aload(&o[1]);
        float tz = aload(&o[2]), tw = aload(&o[3]);
        const float np = aload(&o0[5]), A = aload(&o0[6]), Bv = aload(&o0[7]);
        #pragma unroll
        for (int off = 4; off; off >>= 1) {
            tx += __shfl_xor(tx, off, 8);
            ty += __shfl_xor(ty, off, 8);
            tz += __shfl_xor(tz, off, 8);
            tw += __shfl_xor(tw, off, 8);
        }
        float pl = 0.f, nl = 0.f;
        if ((l & 7) == 0) {
            const float nn = (float)NTOK - np;
            const float pos_term = A - 2.f * tx + np * tz;
            const float neg_term = (Bv - A) - 2.f * ty + nn * tw;
            pl = (np > 0.f) ? pos_term / (fmaxf(np, 1.f) * (float)CH) : 0.f;
            nl = (nn > 0.f) ? neg_term / (fmaxf(nn, 1.f) * (float)CH) : 0.f;
        }
        #pragma unroll
        for (int off = 32; off; off >>= 1) {
            pl += __shfl_xor(pl, off, 64);
            nl += __shfl_xor(nl, off, 64);
        }
        if (l == 0) {
            const float inv_b = 1.f / (float)BATCH;
            out[0] = (pl + nl) * inv_b;    // mean(center_loss)
            out[1] = pl * inv_b;           // mean(pos_loss)
            out[2] = nl * inv_b;           // mean(neg_loss)
        }
    }
}

extern "C" void kernel_launch(void* const* d_in, const int* in_sizes, int n_in,
                              void* d_out, int out_size, void* d_ws, size_t ws_size,
                              hipStream_t stream) {
    const float* ep_e = (const float*)d_in[0];  // ep_mask_embed (8,4096,256)
    const float* ep_m = (const float*)d_in[1];  // ep_mask (8,1,1024,1024)
    const float* q_e  = (const float*)d_in[2];  // query_mask_embed
    const float* q_m  = (const float*)d_in[3];  // query_mask
    float* out = (float*)d_out;
    float* ws  = (float*)d_ws;

    // zero the 9 protocol counters (cnt1[8] + cnt2) each call
    hipMemsetAsync((char*)ws + (size_t)CNTF * sizeof(float), 0,
                   9 * sizeof(unsigned int), stream);
    fused_kernel<<<NBLK_STATS, 256, 0, stream>>>(ep_e, ep_m, q_e, q_m, ws, out);
}

// Round 12
// 21.491 us; speedup vs baseline: 1.4951x; 1.4951x over previous
//
#include <hip/hip_runtime.h>

#define BATCH 8
#define NTOK 4096
#define CH 256
#define IMG 1024
#define PATCH 16
#define CHUNKS 32                    // blocks per (batch, input)
#define TPB (NTOK / CHUNKS)          // 128 tokens per block
#define PART_STRIDE 520              // per-block partial slab (floats)
#define NBLK_STATS (2 * BATCH * CHUNKS)  // 512

// ws layout: slab bid (= is_q*256 + b*32 + chunk), PART_STRIDE floats:
//   [0,256) W  [256,512) S  [512] sum m  [513] sum m*|e|^2  [514] sum |e|^2
//
// Ledger: stats exec ~10.2us (~7 TB/s, at measured ceiling), node cost
// ~2.7us, R9 finalize exec ~5.7us. R12: loss decomposes over channel
// slices (A/np enter once, tx/tz additive) -> 16-block finalize that
// atomicAdds scaled slice contributions straight into out. 2 nodes.

__device__ __forceinline__ float wave_reduce_sum(float v) {
    for (int off = 32; off > 0; off >>= 1) v += __shfl_down(v, off, 64);
    return v;
}

__global__ __launch_bounds__(256) void stats_kernel(
    const float* __restrict__ ep_e, const float* __restrict__ ep_m,
    const float* __restrict__ q_e,  const float* __restrict__ q_m,
    float* __restrict__ ws, float* __restrict__ out)
{
    const int bid = blockIdx.x;
    const int tid = threadIdx.x;
    if (bid == 0 && tid < 3) out[tid] = 0.f;   // finalize accumulates into out

    const bool is_q = (bid >= BATCH * CHUNKS);
    const int lb    = bid & (BATCH * CHUNKS - 1);
    const int b     = lb >> 5;                  // /CHUNKS
    const int start = (lb & (CHUNKS - 1)) * TPB;

    const float* __restrict__ embed = is_q ? q_e : ep_e;
    const float* __restrict__ mask  = is_q ? q_m : ep_m;

    const int w = tid >> 6, lane = tid & 63, cbase = lane << 2;

    float4 accW = {0.f, 0.f, 0.f, 0.f};
    float4 accS = {0.f, 0.f, 0.f, 0.f};
    float accA = 0.f, accB = 0.f, accm = 0.f;

    const float* ebase = embed + (size_t)(b * NTOK + start) * CH + cbase;
    const size_t mbase = (size_t)b * IMG * IMG;

    const int t0 = w * 32;   // this wave's 32 contiguous tokens
    #pragma unroll
    for (int bat = 0; bat < 4; ++bat) {
        float4 e[8];
        float  mm[8];
        #pragma unroll
        for (int k = 0; k < 8; ++k) {
            const int t = t0 + bat * 8 + k;
            const int n = start + t;
            mm[k] = mask[mbase + (size_t)((n >> 6) * PATCH) * IMG + (size_t)((n & 63) * PATCH)];
            e[k]  = *reinterpret_cast<const float4*>(ebase + (size_t)t * CH);
        }
        #pragma unroll
        for (int k = 0; k < 8; ++k) {
            const float m = mm[k];
            accW.x += m * e[k].x; accW.y += m * e[k].y;
            accW.z += m * e[k].z; accW.w += m * e[k].w;
            accS.x += e[k].x;     accS.y += e[k].y;
            accS.z += e[k].z;     accS.w += e[k].w;
            if (is_q) {
                const float d = e[k].x * e[k].x + e[k].y * e[k].y
                              + e[k].z * e[k].z + e[k].w * e[k].w;
                accA += m * d;
                accB += d;
            }
            accm += m;   // wave-uniform
        }
    }

    // cross-wave reduce (all 4 waves cover the same 256 channels)
    __shared__ __align__(16) float ldsW[4][CH];
    __shared__ __align__(16) float ldsS[4][CH];
    __shared__ float ldsA[4], ldsB[4], ldsM[4];

    *reinterpret_cast<float4*>(&ldsW[w][cbase]) = accW;
    *reinterpret_cast<float4*>(&ldsS[w][cbase]) = accS;
    if (is_q) {
        accA = wave_reduce_sum(accA);
        accB = wave_reduce_sum(accB);
    }
    if (lane == 0) { ldsA[w] = accA; ldsB[w] = accB; ldsM[w] = accm; }
    __syncthreads();

    float* p = ws + (size_t)bid * PART_STRIDE;
    const int c = tid;
    p[c]      = ldsW[0][c] + ldsW[1][c] + ldsW[2][c] + ldsW[3][c];
    p[CH + c] = ldsS[0][c] + ldsS[1][c] + ldsS[2][c] + ldsS[3][c];
    if (tid == 0) {
        p[512] = ldsM[0] + ldsM[1] + ldsM[2] + ldsM[3];
        p[513] = is_q ? (ldsA[0] + ldsA[1] + ldsA[2] + ldsA[3]) : 0.f;
        p[514] = is_q ? (ldsB[0] + ldsB[1] + ldsB[2] + ldsB[3]) : 0.f;
    }
}

// 16 blocks: (b, h) = (blockIdx>>1, blockIdx&1); h picks channel half
// [h*128, h*128+128). Each block reduces its half over all 32 chunks
// (64 KB, 16 float4 loads/thread all in flight), computes slice dot
// products, and atomicAdds the scaled contribution directly into out.
__global__ __launch_bounds__(256) void fin_kernel(
    const float* __restrict__ ws, float* __restrict__ out)
{
    const int b   = blockIdx.x >> 1;
    const int h   = blockIdx.x & 1;
    const int tid = threadIdx.x;
    const int r   = tid >> 5;              // chunk row 0..7
    const int c4  = tid & 31;              // float4 group within half
    const int ch  = h * 128 + (c4 << 2);   // channel base

    float4 aW = {0,0,0,0}, aS = {0,0,0,0}, aU = {0,0,0,0}, aV = {0,0,0,0};
    #pragma unroll
    for (int p = 0; p < 4; ++p) {
        const int k = r + 8 * p;
        const float* pe = ws + (size_t)(b * CHUNKS + k) * PART_STRIDE;
        const float* pq = pe + (size_t)(BATCH * CHUNKS) * PART_STRIDE;
        const float4 w4 = *reinterpret_cast<const float4*>(pe + ch);
        const float4 s4 = *reinterpret_cast<const float4*>(pe + CH + ch);
        const float4 u4 = *reinterpret_cast<const float4*>(pq + ch);
        const float4 v4 = *reinterpret_cast<const float4*>(pq + CH + ch);
        aW.x += w4.x; aW.y += w4.y; aW.z += w4.z; aW.w += w4.w;
        aS.x += s4.x; aS.y += s4.y; aS.z += s4.z; aS.w += s4.w;
        aU.x += u4.x; aU.y += u4.y; aU.z += u4.z; aU.w += u4.w;
        aV.x += v4.x; aV.y += v4.y; aV.z += v4.z; aV.w += v4.w;
    }

    // batch scalars: wave 2 (tids 128..191); lanes 0..31 ep, 32..63 q
    __shared__ float sc[4];   // cnt_ep, np, A, Bv
    if (tid >= 128 && tid < 160) {
        const float* pe = ws + (size_t)(b * CHUNKS + (tid - 128)) * PART_STRIDE;
        float v = pe[512];
        #pragma unroll
        for (int off = 16; off; off >>= 1) v += __shfl_xor(v, off, 32);
        if (tid == 128) sc[0] = v;
    } else if (tid >= 160 && tid < 192) {
        const float* pq = ws + (size_t)(BATCH * CHUNKS + b * CHUNKS + (tid - 160)) * PART_STRIDE;
        float n0 = pq[512], a0 = pq[513], b0 = pq[514];
        #pragma unroll
        for (int off = 16; off; off >>= 1) {
            n0 += __shfl_xor(n0, off, 32);
            a0 += __shfl_xor(a0, off, 32);
            b0 += __shfl_xor(b0, off, 32);
        }
        if (tid == 160) { sc[1] = n0; sc[2] = a0; sc[3] = b0; }
    }

    __shared__ __align__(16) float4 L[4][8][32];
    L[0][r][c4] = aW; L[1][r][c4] = aS; L[2][r][c4] = aU; L[3][r][c4] = aV;
    __syncthreads();

    if (tid < 32) {
        float4 PN = L[0][0][tid], SE = L[1][0][tid];
        float4 UU = L[2][0][tid], VV = L[3][0][tid];
        #pragma unroll
        for (int rr = 1; rr < 8; ++rr) {
            const float4 w4 = L[0][rr][tid], s4 = L[1][rr][tid];
            const float4 u4 = L[2][rr][tid], v4 = L[3][rr][tid];
            PN.x += w4.x; PN.y += w4.y; PN.z += w4.z; PN.w += w4.w;
            SE.x += s4.x; SE.y += s4.y; SE.z += s4.z; SE.w += s4.w;
            UU.x += u4.x; UU.y += u4.y; UU.z += u4.z; UU.w += u4.w;
            VV.x += v4.x; VV.y += v4.y; VV.z += v4.z; VV.w += v4.w;
        }
        const float cnt  = sc[0];
        const float id_p = 1.f / (cnt + 0.1f);
        const float id_n = 1.f / (((float)NTOK - cnt) + 0.1f);

        float tx = 0.f, ty = 0.f, tz = 0.f, tw = 0.f;
        #pragma unroll
        for (int i = 0; i < 4; ++i) {
            const float pni = (&PN.x)[i], sei = (&SE.x)[i];
            const float uui = (&UU.x)[i], vvi = (&VV.x)[i];
            const float pc = pni * id_p;
            const float nc = (sei - pni) * id_n;
            tx += uui * pc;          // slice u.p
            ty += (vvi - uui) * nc;  // slice (v-u).n
            tz += pc * pc;           // slice |p|^2
            tw += nc * nc;           // slice |n|^2
        }
        #pragma unroll
        for (int off = 16; off; off >>= 1) {
            tx += __shfl_xor(tx, off, 32);
            ty += __shfl_xor(ty, off, 32);
            tz += __shfl_xor(tz, off, 32);
            tw += __shfl_xor(tw, off, 32);
        }

        if (tid == 0) {
            const float np = sc[1], A = sc[2], Bv = sc[3];
            const float nn = (float)NTOK - np;
            // slice contribution; A / (Bv-A) enter once, via half 0
            float pos_part = -2.f * tx + np * tz;
            float neg_part = -2.f * ty + nn * tw;
            if (h == 0) { pos_part += A; neg_part += (Bv - A); }
            const float pl = (np > 0.f) ? pos_part / (fmaxf(np, 1.f) * (float)CH) : 0.f;
            const float nl = (nn > 0.f) ? neg_part / (fmaxf(nn, 1.f) * (float)CH) : 0.f;
            const float inv_b = 1.f / (float)BATCH;
            atomicAdd(&out[0], (pl + nl) * inv_b);
            atomicAdd(&out[1], pl * inv_b);
            atomicAdd(&out[2], nl * inv_b);
        }
    }
}

extern "C" void kernel_launch(void* const* d_in, const int* in_sizes, int n_in,
                              void* d_out, int out_size, void* d_ws, size_t ws_size,
                              hipStream_t stream) {
    const float* ep_e = (const float*)d_in[0];  // ep_mask_embed (8,4096,256)
    const float* ep_m = (const float*)d_in[1];  // ep_mask (8,1,1024,1024)
    const float* q_e  = (const float*)d_in[2];  // query_mask_embed
    const float* q_m  = (const float*)d_in[3];  // query_mask
    float* out = (float*)d_out;
    float* ws  = (float*)d_ws;

    stats_kernel<<<NBLK_STATS, 256, 0, stream>>>(ep_e, ep_m, q_e, q_m, ws, out);
    fin_kernel<<<2 * BATCH, 256, 0, stream>>>(ws, out);
}